// Round 1
// 4262.392 us; speedup vs baseline: 1.5327x; 1.5327x over previous
//
#include <hip/hip_runtime.h>
#include <stdint.h>

// GRU S=512, B=64, D=H=1024, L=2 — persistent cooperative pipeline, v3.
// 256 WGs = 4 tasks x 64 slices, 1 WG/CU:
//   task0: xlin0[t] = x[t] @ wih0^T + bih0
//   task1: layer-0 GRU step t
//   task2: xlin1[t] = out0[t] @ wih1^T + bih1
//   task3: layer-1 GRU step t -> d_out
// v3 changes vs v2 (theory: hot-line flag RMW/poll serialization dominated):
//   * NO atomic RMW counters. Per-slice store-only flags done0..3[64], each
//     padded to its own 64B line. Producer: one relaxed agent store.
//   * Consumer: wave-0 64-lane parallel poll (lane L polls flag L), monotonic
//     per-lane caching (stop reloading once satisfied), ALL of a step's wait
//     conditions folded into ONE poll loop.
//   * Weights LDS-persistent (96 KB staged once) — no per-step stageB, no
//     mid-step __syncthreads, no vmcnt coupling; also fixes latent chunk-0
//     visibility race.
//   * Ring waits reduced to pairwise where the dependency is per-slice.

#define SLEN 512
#define HB   65536
#define G3   3072
#define XLSLOT (64 * 64 * 48)   // floats per xlin ring slot: [slice][row64][gate3][col16]

typedef __attribute__((ext_vector_type(8))) short bf16x8;
typedef __attribute__((ext_vector_type(4))) float f32x4;
typedef __attribute__((ext_vector_type(8))) uint16_t u16x8;

__device__ __forceinline__ uint16_t f32_to_bf16(float f) {
  uint32_t u = __float_as_uint(f);
  uint32_t r = u + 0x7FFFu + ((u >> 16) & 1u);
  return (uint16_t)(r >> 16);
}
__device__ __forceinline__ float sigmoid_fast(float x) { return 1.0f / (1.0f + __expf(-x)); }
__device__ __forceinline__ float tanh_fast(float x) { return 1.0f - 2.0f / (1.0f + __expf(2.0f * x)); }
__device__ __forceinline__ void async_cp16(const void* g, void* l) {
  __builtin_amdgcn_global_load_lds((const __attribute__((address_space(1))) void*)g,
                                   (__attribute__((address_space(3))) void*)l, 16, 0, 0);
}
__device__ __forceinline__ void st_u16_llc(uint16_t* p, uint16_t v) {
  __hip_atomic_store(p, v, __ATOMIC_RELAXED, __HIP_MEMORY_SCOPE_AGENT);
}
__device__ __forceinline__ void st_f32_llc(float* p, float v) {
  __hip_atomic_store(p, v, __ATOMIC_RELAXED, __HIP_MEMORY_SCOPE_AGENT);
}
__device__ __forceinline__ void drain_vmem() {
  asm volatile("s_waitcnt vmcnt(0)" ::: "memory");
}
__device__ __forceinline__ int ld_flag(const int* p) {
  return __hip_atomic_load(p, __ATOMIC_RELAXED, __HIP_MEMORY_SCOPE_AGENT);
}
__device__ __forceinline__ void st_flag(int* p, int v) {
  __hip_atomic_store(p, v, __ATOMIC_RELAXED, __HIP_MEMORY_SCOPE_AGENT);
}

// ---- prep kernels -----------------------------------------------------------

__global__ __launch_bounds__(256) void convert_x(const float* __restrict__ src,
                                                 uint16_t* __restrict__ dst) {
  size_t i = ((size_t)blockIdx.x * 256 + threadIdx.x) * 8;
  const float4* s = (const float4*)(src + i);
  float4 a = s[0], b = s[1];
  u16x8 v;
  v[0] = f32_to_bf16(a.x); v[1] = f32_to_bf16(a.y);
  v[2] = f32_to_bf16(a.z); v[3] = f32_to_bf16(a.w);
  v[4] = f32_to_bf16(b.x); v[5] = f32_to_bf16(b.y);
  v[6] = f32_to_bf16(b.z); v[7] = f32_to_bf16(b.w);
  *(u16x8*)(dst + i) = v;
}

// (3072x1024 f32, row-major) -> MFMA B-fragment order:
// chunk = (tile*32 + ks)*64 + lane, holding w[16*tile + (lane&15)][32ks + (lane>>4)*8 ..+7]
__global__ __launch_bounds__(256) void pack_w(const float* __restrict__ src,
                                              uint16_t* __restrict__ dst) {
  int tid = blockIdx.x * 256 + threadIdx.x;
  int tile = tid >> 11, rem = tid & 2047, ks = rem >> 6, lane = rem & 63;
  int row = tile * 16 + (lane & 15);
  int k0 = ks * 32 + (lane >> 4) * 8;
  const float* s = src + (size_t)row * 1024 + k0;
  u16x8 v;
#pragma unroll
  for (int j = 0; j < 8; ++j) v[j] = f32_to_bf16(s[j]);
  *(u16x8*)(dst + (size_t)tid * 8) = v;
}

__global__ __launch_bounds__(256) void init_state(const float* __restrict__ hx,
                                                  uint16_t* __restrict__ h0b,
                                                  uint16_t* __restrict__ h1b,
                                                  int* __restrict__ flags) {
  int i = blockIdx.x * 256 + threadIdx.x;   // 65536 threads
  h0b[i] = f32_to_bf16(hx[i]);
  h1b[i] = f32_to_bf16(hx[HB + i]);
  if (blockIdx.x < 16) flags[blockIdx.x * 256 + threadIdx.x] = 0;  // 4096 ints
}

// ---- parallel flag wait -----------------------------------------------------
// Executed by wave 0 only. Conditions (each optional, active iff target > 0):
//   p0[0]        >= t0   (single flag, uniform)
//   pa[lane*16]  >= ta   (all-64 array)
//   pb[lane*16]  >= tb   (all-64 array)
// Monotonic flags => a lane stops reloading once its value passes target.
__device__ __forceinline__ void poll_wait(const int* p0, int t0,
                                          const int* pa, int ta,
                                          const int* pb, int tb, int lane) {
  const int BIG = 0x7fffffff;
  int v0 = (t0 > 0) ? ld_flag(p0) : BIG;
  int va = (ta > 0) ? ld_flag(pa + lane * 16) : BIG;
  int vb = (tb > 0) ? ld_flag(pb + lane * 16) : BIG;
  int it = 0;
  while (!__all((v0 >= t0) & (va >= ta) & (vb >= tb))) {
    __builtin_amdgcn_s_sleep(1);
    if (v0 < t0) v0 = ld_flag(p0);
    if (va < ta) va = ld_flag(pa + lane * 16);
    if (vb < tb) vb = ld_flag(pb + lane * 16);
    if (++it > (1 << 24)) break;   // safety valve vs hang
  }
}

// ---- device-scope (sc1) load batches ---------------------------------------

__device__ __forceinline__ void load_a16_sc1(const uint16_t* p, bf16x8* a) {
  asm volatile(
      "global_load_dwordx4 %0, %16, off sc1\n\t"
      "global_load_dwordx4 %1, %16, off offset:64 sc1\n\t"
      "global_load_dwordx4 %2, %16, off offset:128 sc1\n\t"
      "global_load_dwordx4 %3, %16, off offset:192 sc1\n\t"
      "global_load_dwordx4 %4, %16, off offset:256 sc1\n\t"
      "global_load_dwordx4 %5, %16, off offset:320 sc1\n\t"
      "global_load_dwordx4 %6, %16, off offset:384 sc1\n\t"
      "global_load_dwordx4 %7, %16, off offset:448 sc1\n\t"
      "global_load_dwordx4 %8, %16, off offset:512 sc1\n\t"
      "global_load_dwordx4 %9, %16, off offset:576 sc1\n\t"
      "global_load_dwordx4 %10, %16, off offset:640 sc1\n\t"
      "global_load_dwordx4 %11, %16, off offset:704 sc1\n\t"
      "global_load_dwordx4 %12, %16, off offset:768 sc1\n\t"
      "global_load_dwordx4 %13, %16, off offset:832 sc1\n\t"
      "global_load_dwordx4 %14, %16, off offset:896 sc1\n\t"
      "global_load_dwordx4 %15, %16, off offset:960 sc1\n\t"
      "s_waitcnt vmcnt(0)"
      : "=&v"(a[0]), "=&v"(a[1]), "=&v"(a[2]), "=&v"(a[3]),
        "=&v"(a[4]), "=&v"(a[5]), "=&v"(a[6]), "=&v"(a[7]),
        "=&v"(a[8]), "=&v"(a[9]), "=&v"(a[10]), "=&v"(a[11]),
        "=&v"(a[12]), "=&v"(a[13]), "=&v"(a[14]), "=&v"(a[15])
      : "v"(p)
      : "memory");
}

// 16 A-fragments + 12 xlin floats (offsets rg*192 + g*64), one vmcnt(0).
__device__ __forceinline__ void load_a16_xl12_sc1(const uint16_t* p, const float* px,
                                                  bf16x8* a, float* x) {
  asm volatile(
      "global_load_dword %16, %29, off sc1\n\t"
      "global_load_dword %17, %29, off offset:64 sc1\n\t"
      "global_load_dword %18, %29, off offset:128 sc1\n\t"
      "global_load_dword %19, %29, off offset:192 sc1\n\t"
      "global_load_dword %20, %29, off offset:256 sc1\n\t"
      "global_load_dword %21, %29, off offset:320 sc1\n\t"
      "global_load_dword %22, %29, off offset:384 sc1\n\t"
      "global_load_dword %23, %29, off offset:448 sc1\n\t"
      "global_load_dword %24, %29, off offset:512 sc1\n\t"
      "global_load_dword %25, %29, off offset:576 sc1\n\t"
      "global_load_dword %26, %29, off offset:640 sc1\n\t"
      "global_load_dword %27, %29, off offset:704 sc1\n\t"
      "global_load_dwordx4 %0, %28, off sc1\n\t"
      "global_load_dwordx4 %1, %28, off offset:64 sc1\n\t"
      "global_load_dwordx4 %2, %28, off offset:128 sc1\n\t"
      "global_load_dwordx4 %3, %28, off offset:192 sc1\n\t"
      "global_load_dwordx4 %4, %28, off offset:256 sc1\n\t"
      "global_load_dwordx4 %5, %28, off offset:320 sc1\n\t"
      "global_load_dwordx4 %6, %28, off offset:384 sc1\n\t"
      "global_load_dwordx4 %7, %28, off offset:448 sc1\n\t"
      "global_load_dwordx4 %8, %28, off offset:512 sc1\n\t"
      "global_load_dwordx4 %9, %28, off offset:576 sc1\n\t"
      "global_load_dwordx4 %10, %28, off offset:640 sc1\n\t"
      "global_load_dwordx4 %11, %28, off offset:704 sc1\n\t"
      "global_load_dwordx4 %12, %28, off offset:768 sc1\n\t"
      "global_load_dwordx4 %13, %28, off offset:832 sc1\n\t"
      "global_load_dwordx4 %14, %28, off offset:896 sc1\n\t"
      "global_load_dwordx4 %15, %28, off offset:960 sc1\n\t"
      "s_waitcnt vmcnt(0)"
      : "=&v"(a[0]), "=&v"(a[1]), "=&v"(a[2]), "=&v"(a[3]),
        "=&v"(a[4]), "=&v"(a[5]), "=&v"(a[6]), "=&v"(a[7]),
        "=&v"(a[8]), "=&v"(a[9]), "=&v"(a[10]), "=&v"(a[11]),
        "=&v"(a[12]), "=&v"(a[13]), "=&v"(a[14]), "=&v"(a[15]),
        "=&v"(x[0]), "=&v"(x[1]), "=&v"(x[2]), "=&v"(x[3]),
        "=&v"(x[4]), "=&v"(x[5]), "=&v"(x[6]), "=&v"(x[7]),
        "=&v"(x[8]), "=&v"(x[9]), "=&v"(x[10]), "=&v"(x[11])
      : "v"(p), "v"(px)
      : "memory");
}

// ---- persistent kernel ------------------------------------------------------

// B fragments for 16 K-chunks starting at bbase; gate stride 16384 u16 (32 KB).
__device__ __forceinline__ void mfma16(const bf16x8* av, const uint16_t* bbase, int lane,
                                       f32x4& acc0, f32x4& acc1, f32x4& acc2) {
#pragma unroll
  for (int ks = 0; ks < 16; ++ks) {
    const uint16_t* bp = bbase + (size_t)(ks * 64 + lane) * 8;
    bf16x8 b0 = *(const bf16x8*)(bp);
    bf16x8 b1 = *(const bf16x8*)(bp + 16384);
    bf16x8 b2 = *(const bf16x8*)(bp + 32768);
    acc0 = __builtin_amdgcn_mfma_f32_16x16x32_bf16(av[ks], b0, acc0, 0, 0, 0);
    acc1 = __builtin_amdgcn_mfma_f32_16x16x32_bf16(av[ks], b1, acc1, 0, 0, 0);
    acc2 = __builtin_amdgcn_mfma_f32_16x16x32_bf16(av[ks], b2, acc2, 0, 0, 0);
  }
}

__global__ __launch_bounds__(256, 1) void gru_persist(
    const uint16_t* __restrict__ x_bf,
    const uint16_t* __restrict__ wih0, const uint16_t* __restrict__ whh0,
    const uint16_t* __restrict__ wih1, const uint16_t* __restrict__ whh1,
    const float* __restrict__ bih0, const float* __restrict__ bhh0,
    const float* __restrict__ bih1, const float* __restrict__ bhh1,
    const float* __restrict__ hx,
    float* __restrict__ xl0, float* __restrict__ xl1,
    uint16_t* __restrict__ o0r,
    uint16_t* __restrict__ h0b, uint16_t* __restrict__ h1b,
    int* __restrict__ flags,
    float* __restrict__ out) {
  // 96 KB: the WG's FULL B slice (3 gates x K=1024 x 16 cols), LDS-persistent.
  __shared__ uint16_t blds[49152];

  const int task = blockIdx.x >> 6;
  const int slice = blockIdx.x & 63;
  const int tid = threadIdx.x;
  const int lane = tid & 63;
  const int wv = tid >> 6;
  const int r15 = lane & 15;
  const int q = lane >> 4;
  const int c = slice * 16 + r15;           // output column
  const int m = 16 * wv + 4 * q;            // batch row base

  // store-only flags, one 64B line per slice: doneT[slice*16] = steps completed
  int* done0 = flags;
  int* done1 = flags + 1024;
  int* done2 = flags + 2048;
  int* done3 = flags + 3072;
  int* mydone = (task == 0) ? done0 : (task == 1) ? done1 : (task == 2) ? done2 : done3;

  const uint16_t* Bw = (task == 0) ? wih0 : (task == 1) ? whh0 : (task == 2) ? wih1 : whh1;
  const float* bv = (task == 0) ? bih0 : (task == 1) ? bhh0 : (task == 2) ? bih1 : bhh1;
  const float br = bv[c], bz = bv[1024 + c], bn = bv[2048 + c];

  float hreg[4];
  if (task == 1 || task == 3) {
    const int layer = (task == 3);
#pragma unroll
    for (int rg = 0; rg < 4; ++rg)
      hreg[rg] = hx[(size_t)layer * HB + (size_t)(m + rg) * 1024 + c];
  }

  // ---- one-time weight stage: 6144 chunks of 16B -> blds (wave-linear dest)
#pragma unroll
  for (int i = 0; i < 24; ++i) {
    int s2 = i * 256 + tid;                 // (g, ks, l)
    int g = s2 >> 11, rem = s2 & 2047, ks = rem >> 6, l = rem & 63;
    const uint16_t* gp = Bw + (size_t)(g * 64 + slice) * 16384 +
                         (size_t)ks * 512 + l * 8;
    async_cp16(gp, blds + (size_t)s2 * 8);
  }
  drain_vmem();
  __syncthreads();                          // all waves' chunks resident

  for (int t = 0; t < SLEN; ++t) {
    // ---- single combined wait per step (wave 0 polls, others park) ----
    if (wv == 0) {
      if (task == 0) {
        poll_wait(done1 + slice * 16, t - 3, flags, 0, flags, 0, lane);   // xl0 slot free (pairwise)
      } else if (task == 1) {
        poll_wait(done0 + slice * 16, t + 1,   // xlin0[t] slice ready
                  done1, t,                    // h0[t] complete + ping-pong safe
                  done2, t - 3, lane);         // o0r slot free
      } else if (task == 2) {
        poll_wait(done3 + slice * 16, t - 3,   // xl1 slot free (pairwise)
                  done1, t + 1,                // out0[t] complete
                  flags, 0, lane);
      } else {
        poll_wait(done2 + slice * 16, t + 1,   // xlin1[t] slice ready
                  done3, t,                    // h1[t] complete + ping-pong safe
                  flags, 0, lane);
      }
    }
    __syncthreads();

    f32x4 acc0 = {0.f, 0.f, 0.f, 0.f}, acc1 = acc0, acc2 = acc0;
    bf16x8 av[16];
    float xv[12];

    if (task == 1 || task == 3) {
      const uint16_t* hb = (task == 1) ? h0b : h1b;
      const float* xlr = (task == 1) ? xl0 : xl1;
      const uint16_t* ap = hb + (size_t)(t & 1) * HB + (size_t)(16 * wv + r15) * 1024 + q * 8;
      const float* xlp = xlr + (size_t)(t & 3) * XLSLOT + (size_t)(slice * 64 + m) * 48 + r15;

      load_a16_xl12_sc1(ap, xlp, av, xv);   // h half 0 + xlin, device-coherent
      mfma16(av, blds, lane, acc0, acc1, acc2);
      load_a16_sc1(ap + 512, av);           // h half 1
      mfma16(av, blds + 8192, lane, acc0, acc1, acc2);

      uint16_t* hbw = ((task == 1) ? h0b : h1b) + (size_t)((t + 1) & 1) * HB;
      uint16_t* orow = o0r + (size_t)(t & 3) * HB;
#pragma unroll
      for (int rg = 0; rg < 4; ++rg) {
        int mm = m + rg;
        float r = sigmoid_fast(xv[rg * 3 + 0] + acc0[rg] + br);
        float z = sigmoid_fast(xv[rg * 3 + 1] + acc1[rg] + bz);
        float n = tanh_fast(xv[rg * 3 + 2] + r * (acc2[rg] + bn));
        float h = (1.0f - z) * n + z * hreg[rg];
        hreg[rg] = h;
        uint16_t hb16 = f32_to_bf16(h);
        st_u16_llc(hbw + (size_t)mm * 1024 + c, hb16);     // sc1 write-through
        if (task == 1) st_u16_llc(orow + (size_t)mm * 1024 + c, hb16);
        else out[(size_t)t * HB + (size_t)mm * 1024 + c] = h;   // host-only: normal
      }
    } else {
      if (task == 0) {
        const uint16_t* ap = x_bf + (size_t)t * HB + (size_t)(16 * wv + r15) * 1024 + q * 8;
#pragma unroll
        for (int ks = 0; ks < 16; ++ks) av[ks] = *(const bf16x8*)(ap + ks * 32);
        mfma16(av, blds, lane, acc0, acc1, acc2);
#pragma unroll
        for (int ks = 0; ks < 16; ++ks) av[ks] = *(const bf16x8*)(ap + 512 + ks * 32);
        mfma16(av, blds + 8192, lane, acc0, acc1, acc2);
      } else {
        const uint16_t* ap = o0r + (size_t)(t & 3) * HB + (size_t)(16 * wv + r15) * 1024 + q * 8;
        load_a16_sc1(ap, av);
        mfma16(av, blds, lane, acc0, acc1, acc2);
        load_a16_sc1(ap + 512, av);
        mfma16(av, blds + 8192, lane, acc0, acc1, acc2);
      }
      float* dst = ((task == 0) ? xl0 : xl1) + (size_t)(t & 3) * XLSLOT + (size_t)slice * 64 * 48;
#pragma unroll
      for (int rg = 0; rg < 4; ++rg) {
        int mm = m + rg;
        st_f32_llc(dst + (size_t)mm * 48 + r15,      acc0[rg] + br);
        st_f32_llc(dst + (size_t)mm * 48 + 16 + r15, acc1[rg] + bz);
        st_f32_llc(dst + (size_t)mm * 48 + 32 + r15, acc2[rg] + bn);
      }
    }

    drain_vmem();                           // per-wave: this wave's stores at LLC
    __syncthreads();                        // => ALL waves' stores at LLC
    if (tid == 0) st_flag(mydone + slice * 16, t + 1);   // store-only signal
  }

  // final hidden state (L,B,H) appended after out sequence
  if (task == 1 || task == 3) {
    const int layer = (task == 3);
#pragma unroll
    for (int rg = 0; rg < 4; ++rg)
      out[(size_t)SLEN * HB + (size_t)layer * HB + (size_t)(m + rg) * 1024 + c] = hreg[rg];
  }
}

// ---- host -------------------------------------------------------------------

extern "C" void kernel_launch(void* const* d_in, const int* in_sizes, int n_in,
                              void* d_out, int out_size, void* d_ws, size_t ws_size,
                              hipStream_t stream) {
  (void)in_sizes; (void)n_in; (void)out_size; (void)ws_size;
  const float* x = (const float*)d_in[0];
  const float* hx = (const float*)d_in[1];
  const float* wih0f = (const float*)d_in[2];
  const float* whh0f = (const float*)d_in[3];
  const float* bih0 = (const float*)d_in[4];
  const float* bhh0 = (const float*)d_in[5];
  const float* wih1f = (const float*)d_in[6];
  const float* whh1f = (const float*)d_in[7];
  const float* bih1 = (const float*)d_in[8];
  const float* bhh1 = (const float*)d_in[9];
  float* out = (float*)d_out;

  char* ws = (char*)d_ws;
  uint16_t* x_bf = (uint16_t*)ws; ws += (size_t)SLEN * HB * 2;     // 64 MB
  uint16_t* wih0 = (uint16_t*)ws; ws += (size_t)G3 * 1024 * 2;     // 6 MB each
  uint16_t* whh0 = (uint16_t*)ws; ws += (size_t)G3 * 1024 * 2;
  uint16_t* wih1 = (uint16_t*)ws; ws += (size_t)G3 * 1024 * 2;
  uint16_t* whh1 = (uint16_t*)ws; ws += (size_t)G3 * 1024 * 2;
  float* xl0 = (float*)ws; ws += (size_t)4 * XLSLOT * 4;           // 3 MB ring
  float* xl1 = (float*)ws; ws += (size_t)4 * XLSLOT * 4;           // 3 MB ring
  uint16_t* o0r = (uint16_t*)ws; ws += (size_t)4 * HB * 2;         // 512 KB ring
  uint16_t* h0b = (uint16_t*)ws; ws += (size_t)2 * HB * 2;
  uint16_t* h1b = (uint16_t*)ws; ws += (size_t)2 * HB * 2;
  int* flags = (int*)ws; ws += 16384;                              // 4096 ints, 64B-padded flags

  convert_x<<<16384, 256, 0, stream>>>(x, x_bf);
  pack_w<<<1536, 256, 0, stream>>>(wih0f, wih0);
  pack_w<<<1536, 256, 0, stream>>>(whh0f, whh0);
  pack_w<<<1536, 256, 0, stream>>>(wih1f, wih1);
  pack_w<<<1536, 256, 0, stream>>>(whh1f, whh1);
  init_state<<<256, 256, 0, stream>>>(hx, h0b, h1b, flags);

  const uint16_t* cx = x_bf;
  const uint16_t* cw0 = wih0; const uint16_t* cw1 = whh0;
  const uint16_t* cw2 = wih1; const uint16_t* cw3 = whh1;
  void* args[] = {(void*)&cx, (void*)&cw0, (void*)&cw1, (void*)&cw2, (void*)&cw3,
                  (void*)&bih0, (void*)&bhh0, (void*)&bih1, (void*)&bhh1, (void*)&hx,
                  (void*)&xl0, (void*)&xl1, (void*)&o0r, (void*)&h0b, (void*)&h1b,
                  (void*)&flags, (void*)&out};
  hipError_t e = hipLaunchCooperativeKernel(reinterpret_cast<void*>(gru_persist),
                                            dim3(256), dim3(256), args, 0u, stream);
  if (e != hipSuccess) {
    gru_persist<<<dim3(256), dim3(256), 0, stream>>>(
        x_bf, wih0, whh0, wih1, whh1, bih0, bhh0, bih1, bhh1, hx,
        xl0, xl1, o0r, h0b, h1b, flags, out);
  }
}